// Round 7
// baseline (494.856 us; speedup 1.0000x reference)
//
#include <hip/hip_runtime.h>
#include <hip/hip_bf16.h>

#define B_TOT   16384
#define D_IN    784
#define H_DIM   100
#define C_DIM   10
#define HP      128
#define KP      832     // 13 * 64, padded K
#define NDR     13
#define WG_ROWS 32

typedef __bf16 bf16x8 __attribute__((ext_vector_type(8)));
typedef float  f32x4  __attribute__((ext_vector_type(4)));
typedef unsigned short u16x8 __attribute__((ext_vector_type(8)));

static __device__ __forceinline__ unsigned short f32_to_bf16(float f) {
    unsigned int u = __float_as_uint(f);
    unsigned int r = (u + 0x7FFFu + ((u >> 16) & 1u)) >> 16;
    return (unsigned short)r;
}

// ---------------- diagnostic µbenches (sink into d_out; snn_main overwrites) ----------------

__global__ __launch_bounds__(256)
void bw_lin(const f32x4* __restrict__ src, float* __restrict__ sink, int iters, int rep) {
    const int g = blockIdx.x * 256 + threadIdx.x;
    const long stride = (long)gridDim.x * 256;
    float acc = 0.f;
    for (int rp = 0; rp < rep; ++rp) {
#pragma unroll 7
        for (int s = 0; s < iters; ++s) {
            f32x4 v = src[(long)g + (long)s * stride];
            acc += v[0] + v[1] + v[2] + v[3];
        }
        asm volatile("" ::: "memory");   // forbid cross-sweep load reuse
    }
    if ((threadIdx.x & 63) == 0) sink[blockIdx.x * 4 + (threadIdx.x >> 6)] = acc;
}

__global__ __launch_bounds__(256)
void bw_nt(const f32x4* __restrict__ src, float* __restrict__ sink, int iters, int rep) {
    const int g = blockIdx.x * 256 + threadIdx.x;
    const long stride = (long)gridDim.x * 256;
    float acc = 0.f;
    for (int rp = 0; rp < rep; ++rp) {
#pragma unroll 7
        for (int s = 0; s < iters; ++s) {
            f32x4 v = __builtin_nontemporal_load(&src[(long)g + (long)s * stride]);
            acc += v[0] + v[1] + v[2] + v[3];
        }
        asm volatile("" ::: "memory");
    }
    if ((threadIdx.x & 63) == 0) sink[blockIdx.x * 4 + (threadIdx.x >> 6)] = acc;
}

__global__ __launch_bounds__(256)
void bw_pat(const float* __restrict__ rnd, float* __restrict__ sink, int rep) {
    const int tid = threadIdx.x;
    const int sr = tid >> 3, scg = tid & 7;
    const size_t base = ((size_t)blockIdx.x * WG_ROWS + sr) * D_IN;
    const size_t BD = (size_t)B_TOT * D_IN;
    float acc = 0.f;
    for (int rp = 0; rp < rep; ++rp) {
        for (int tp = 0; tp < 2; ++tp)
            for (int dr = 0; dr < NDR; ++dr) {
                const int gd = dr * 64 + scg * 8;
                if (gd + 8 <= D_IN) {
                    for (int tt = 0; tt < 4; ++tt) {
                        const f32x4* p = reinterpret_cast<const f32x4*>(
                            rnd + (size_t)(tp * 4 + tt) * BD + base + gd);
                        f32x4 a = p[0], b = p[1];
                        acc += a[0]+a[1]+a[2]+a[3]+b[0]+b[1]+b[2]+b[3];
                    }
                }
            }
        asm volatile("" ::: "memory");
    }
    if ((tid & 63) == 0) sink[blockIdx.x * 4 + (tid >> 6)] = acc;
}

// ---------------- prep (unchanged) ----------------

__global__ void prep_kernel(const float* __restrict__ W1, const float* __restrict__ b1,
                            unsigned short* __restrict__ w1hi, unsigned short* __restrict__ w1lo,
                            float* __restrict__ b1p) {
    int idx = blockIdx.x * 256 + threadIdx.x;
    if (idx < HP) b1p[idx] = (idx < H_DIM) ? b1[idx] : 0.0f;
    if (idx < HP * KP) {
        int h = idx / KP, k = idx - h * KP;
        float v = (h < H_DIM && k < D_IN) ? W1[h * D_IN + k] : 0.0f;
        unsigned short hi = f32_to_bf16(v);
        float fh = __uint_as_float(((unsigned int)hi) << 16);
        unsigned short lo = f32_to_bf16(v - fh);
        w1hi[idx] = hi;
        w1lo[idx] = lo;
    }
}

// ---------------- main kernel: verbatim round-1 structure (known-pass, 208 µs) ----------------

__global__ __launch_bounds__(256, 2)
void snn_main(const float* __restrict__ inp, const float* __restrict__ rnd,
              const unsigned short* __restrict__ w1hi, const unsigned short* __restrict__ w1lo,
              const float* __restrict__ b1p, const float* __restrict__ W2,
              const float* __restrict__ b2, float* __restrict__ out)
{
    __shared__ __align__(16) unsigned short s_spike[WG_ROWS * 64]; // 4 KB, XOR-swizzled
    __shared__ float s_cnt[WG_ROWS][HP];                           // 16 KB

    const int tid  = threadIdx.x;
    const int lane = tid & 63;
    const int wid  = tid >> 6;
    const int m_off = (wid >> 1) * 16;
    const int n_off = (wid & 1) * 64;
    const int row0 = blockIdx.x * WG_ROWS;

    const int l15 = lane & 15;
    const int l4  = lane >> 4;

    float b1f[4];
#pragma unroll
    for (int nt = 0; nt < 4; ++nt) b1f[nt] = b1p[n_off + nt * 16 + l15];

    f32x4 mem1[4], cnt[4];
#pragma unroll
    for (int nt = 0; nt < 4; ++nt) { mem1[nt] = (f32x4)0.0f; cnt[nt] = (f32x4)0.0f; }

    const int sr  = tid >> 3;
    const int scg = tid & 7;
    const size_t inp_base = (size_t)(row0 + sr) * D_IN;
    const int swByte = (sr * 8 + (scg ^ (sr & 7))) * 16;

    for (int tp = 0; tp < 2; ++tp) {
        f32x4 acc[4][4];
#pragma unroll
        for (int a_ = 0; a_ < 4; ++a_)
#pragma unroll
            for (int b_ = 0; b_ < 4; ++b_) acc[a_][b_] = (f32x4)0.0f;

        for (int dr = 0; dr < NDR; ++dr) {
            const int kbase = dr * 64;
            bf16x8 bh[2][4], blo[2][4];
#pragma unroll
            for (int c = 0; c < 2; ++c)
#pragma unroll
                for (int nt = 0; nt < 4; ++nt) {
                    int off = (n_off + nt * 16 + l15) * KP + kbase + c * 32 + l4 * 8;
                    bh[c][nt]  = *reinterpret_cast<const bf16x8*>(w1hi + off);
                    blo[c][nt] = *reinterpret_cast<const bf16x8*>(w1lo + off);
                }

#pragma unroll
            for (int tt = 0; tt < 4; ++tt) {
                const int t = tp * 4 + tt;
                __syncthreads();
                {
                    const int gd = kbase + scg * 8;
                    u16x8 v = (u16x8)0;
                    if (gd + 8 <= D_IN) {
                        const f32x4* rp = reinterpret_cast<const f32x4*>(
                            rnd + (size_t)t * ((size_t)B_TOT * D_IN) + inp_base + gd);
                        const f32x4* ip = reinterpret_cast<const f32x4*>(inp + inp_base + gd);
                        f32x4 r0 = rp[0], r1 = rp[1];
                        f32x4 i0 = ip[0], i1 = ip[1];
                        float xs[8] = {i0[0],i0[1],i0[2],i0[3],i1[0],i1[1],i1[2],i1[3]};
                        float rs[8] = {r0[0],r0[1],r0[2],r0[3],r1[0],r1[1],r1[2],r1[3]};
#pragma unroll
                        for (int j = 0; j < 8; ++j) {
                            unsigned short sg = xs[j] > 0.0f ? (unsigned short)0x3F80
                                              : (xs[j] < 0.0f ? (unsigned short)0xBF80
                                                              : (unsigned short)0);
                            v[j] = (rs[j] * 2.0f <= fabsf(xs[j])) ? sg : (unsigned short)0;
                        }
                    }
                    *reinterpret_cast<u16x8*>(reinterpret_cast<char*>(s_spike) + swByte) = v;
                }
                __syncthreads();
#pragma unroll
                for (int c = 0; c < 2; ++c) {
                    const int rr = m_off + l15;
                    const int g = (c * 4 + l4) ^ (rr & 7);
                    bf16x8 a = *reinterpret_cast<const bf16x8*>(
                        reinterpret_cast<const char*>(s_spike) + rr * 128 + g * 16);
#pragma unroll
                    for (int nt = 0; nt < 4; ++nt) {
                        acc[tt][nt] = __builtin_amdgcn_mfma_f32_16x16x32_bf16(a, bh[c][nt],  acc[tt][nt], 0, 0, 0);
                        acc[tt][nt] = __builtin_amdgcn_mfma_f32_16x16x32_bf16(a, blo[c][nt], acc[tt][nt], 0, 0, 0);
                    }
                }
            }
        }
#pragma unroll
        for (int tt = 0; tt < 4; ++tt)
#pragma unroll
            for (int nt = 0; nt < 4; ++nt)
#pragma unroll
                for (int r = 0; r < 4; ++r) {
                    float m = 0.95f * mem1[nt][r] + acc[tt][nt][r];
                    m = m + b1f[nt];
                    float o = (m > 1.0f) ? 1.0f : 0.0f;
                    mem1[nt][r] = m - o;
                    cnt[nt][r] += o;
                }
    }

    __syncthreads();
#pragma unroll
    for (int nt = 0; nt < 4; ++nt)
#pragma unroll
        for (int r = 0; r < 4; ++r)
            s_cnt[m_off + l4 * 4 + r][n_off + nt * 16 + l15] = cnt[nt][r];
    __syncthreads();
    for (int idx = tid; idx < WG_ROWS * C_DIM; idx += 256) {
        int bl_ = idx / C_DIM, c = idx - bl_ * C_DIM;
        float s = 0.0f;
        for (int h = 0; h < H_DIM; ++h) s += s_cnt[bl_][h] * W2[c * H_DIM + h];
        out[(size_t)(row0 + bl_) * C_DIM + c] = s * 0.125f + b2[c];
    }
}

extern "C" void kernel_launch(void* const* d_in, const int* in_sizes, int n_in,
                              void* d_out, int out_size, void* d_ws, size_t ws_size,
                              hipStream_t stream) {
    const float* inp = (const float*)d_in[0];
    const float* rnd = (const float*)d_in[1];
    const float* W1  = (const float*)d_in[2];
    const float* b1  = (const float*)d_in[3];
    const float* W2  = (const float*)d_in[4];
    const float* b2  = (const float*)d_in[5];
    float* out = (float*)d_out;

    unsigned short* w1hi = (unsigned short*)d_ws;
    unsigned short* w1lo = w1hi + HP * KP;
    float* b1p = (float*)(w1lo + HP * KP);

    // ---- diagnostics: sink into d_out regions; snn_main overwrites ALL of d_out after ----
    const int NV4 = (B_TOT / 2) * D_IN;              // 25,690,112 float4s in rand
    const f32x4* rnd4 = (const f32x4*)rnd;
    bw_lin<<<2048, 256, 0, stream>>>(rnd4, out,         NV4 / (2048 * 256), 5); // A: stream health
    bw_nt <<<2048, 256, 0, stream>>>(rnd4, out + 8192,  NV4 / (2048 * 256), 5); // B: nt flag
    bw_pat<<< 512, 256, 0, stream>>>(rnd,  out + 16384, 4);                     // C: R1 pattern
    bw_lin<<< 512, 256, 0, stream>>>(rnd4, out + 18432, NV4 / (512 * 256),  4); // D: 512-WG TLP

    prep_kernel<<<(HP * KP + 255) / 256, 256, 0, stream>>>(W1, b1, w1hi, w1lo, b1p);
    snn_main<<<B_TOT / WG_ROWS, 256, 0, stream>>>(inp, rnd, w1hi, w1lo, b1p, W2, b2, out);
}

// Round 8
// 240.939 us; speedup vs baseline: 2.0539x; 2.0539x over previous
//
#include <hip/hip_runtime.h>
#include <hip/hip_bf16.h>

#define B_TOT   16384
#define D_IN    784
#define H_DIM   100
#define C_DIM   10
#define HP      128
#define KP      832     // 13 * 64, padded K
#define NDR     13
#define WG_ROWS 32
#define WPR     49      // packed u32 words per row (784 / 16)
#define NWORDS  (8 * B_TOT * WPR)   // 6,422,528 packed words

typedef __bf16 bf16x8 __attribute__((ext_vector_type(8)));
typedef float  f32x4  __attribute__((ext_vector_type(4)));
typedef unsigned short u16x8 __attribute__((ext_vector_type(8)));

static __device__ __forceinline__ unsigned short f32_to_bf16(float f) {
    unsigned int u = __float_as_uint(f);
    unsigned int r = (u + 0x7FFFu + ((u >> 16) & 1u)) >> 16;
    return (unsigned short)r;
}

__global__ void prep_kernel(const float* __restrict__ W1, const float* __restrict__ b1,
                            unsigned short* __restrict__ w1hi, unsigned short* __restrict__ w1lo,
                            float* __restrict__ b1p) {
    int idx = blockIdx.x * 256 + threadIdx.x;
    if (idx < HP) b1p[idx] = (idx < H_DIM) ? b1[idx] : 0.0f;
    if (idx < HP * KP) {
        int h = idx / KP, k = idx - h * KP;
        float v = (h < H_DIM && k < D_IN) ? W1[h * D_IN + k] : 0.0f;
        unsigned short hi = f32_to_bf16(v);
        float fh = __uint_as_float(((unsigned int)hi) << 16);
        unsigned short lo = f32_to_bf16(v - fh);
        w1hi[idx] = hi;
        w1lo[idx] = lo;
    }
}

// ---------------- Phase A: pure-stream spike packing (bw_lin-shaped) ----------------
// word w covers rand elements [16w, 16w+16); bit 2e = fire, bit 2e+1 = negative.
__global__ __launch_bounds__(256)
void spike_pack(const float* __restrict__ inp, const float* __restrict__ rnd,
                unsigned* __restrict__ packed) {
    const int stride = gridDim.x * 256;
    for (int w = blockIdx.x * 256 + threadIdx.x; w < NWORDS; w += stride) {
        const f32x4* rp = reinterpret_cast<const f32x4*>(rnd) + (size_t)w * 4;
        int rem = w % (B_TOT * WPR);
        int b = rem / WPR, g = rem - b * WPR;
        const f32x4* ip = reinterpret_cast<const f32x4*>(inp + (size_t)b * D_IN + g * 16);
        unsigned bits = 0;
#pragma unroll
        for (int q = 0; q < 4; ++q) {
            f32x4 r = rp[q];
            f32x4 x = ip[q];
#pragma unroll
            for (int j = 0; j < 4; ++j) {
                const int e = q * 4 + j;
                unsigned fire = (r[j] * 2.0f <= fabsf(x[j])) && (x[j] != 0.0f);
                unsigned neg  = (x[j] < 0.0f);
                bits |= (fire << (2 * e)) | (neg << (2 * e + 1));
            }
        }
        packed[w] = bits;
    }
}

// ---------------- Phase B: GEMM from LDS-resident packed spikes (R1 numerics) ----------------
__global__ __launch_bounds__(256, 2)
void snn_gemm(const unsigned* __restrict__ packed,
              const unsigned short* __restrict__ w1hi, const unsigned short* __restrict__ w1lo,
              const float* __restrict__ b1p, const float* __restrict__ W2,
              const float* __restrict__ b2, float* __restrict__ out)
{
    __shared__ unsigned s_packed[8 * WG_ROWS * WPR];               // 50,176 B
    __shared__ __align__(16) unsigned short s_spike[WG_ROWS * 64]; // 4 KB, XOR-swizzled
    __shared__ float s_cnt[WG_ROWS][HP];                           // 16 KB

    const int tid  = threadIdx.x;
    const int lane = tid & 63;
    const int wid  = tid >> 6;
    const int m_off = (wid >> 1) * 16;
    const int n_off = (wid & 1) * 64;
    const int row0 = blockIdx.x * WG_ROWS;

    const int l15 = lane & 15;
    const int l4  = lane >> 4;

    // ---- upfront: all 8 timesteps' packed spikes -> LDS (deep, coalesced, no deps) ----
#pragma unroll
    for (int t = 0; t < 8; ++t) {
        const unsigned* src = packed + ((size_t)t * B_TOT + row0) * WPR;
#pragma unroll
        for (int i = 0; i < 7; ++i) {
            int w = tid + i * 256;
            if (w < WG_ROWS * WPR) s_packed[t * (WG_ROWS * WPR) + w] = src[w];
        }
    }

    float b1f[4];
#pragma unroll
    for (int nt = 0; nt < 4; ++nt) b1f[nt] = b1p[n_off + nt * 16 + l15];

    f32x4 mem1[4], cnt[4];
#pragma unroll
    for (int nt = 0; nt < 4; ++nt) { mem1[nt] = (f32x4)0.0f; cnt[nt] = (f32x4)0.0f; }

    const int sr  = tid >> 3;
    const int scg = tid & 7;
    const int swByte = (sr * 8 + (scg ^ (sr & 7))) * 16;

    __syncthreads();   // s_packed visible

    for (int tp = 0; tp < 2; ++tp) {
        f32x4 acc[4][4];
#pragma unroll
        for (int a_ = 0; a_ < 4; ++a_)
#pragma unroll
            for (int b_ = 0; b_ < 4; ++b_) acc[a_][b_] = (f32x4)0.0f;

        for (int dr = 0; dr < NDR; ++dr) {
            const int kbase = dr * 64;
            bf16x8 bh[2][4], blo[2][4];
#pragma unroll
            for (int c = 0; c < 2; ++c)
#pragma unroll
                for (int nt = 0; nt < 4; ++nt) {
                    int off = (n_off + nt * 16 + l15) * KP + kbase + c * 32 + l4 * 8;
                    bh[c][nt]  = *reinterpret_cast<const bf16x8*>(w1hi + off);
                    blo[c][nt] = *reinterpret_cast<const bf16x8*>(w1lo + off);
                }

#pragma unroll
            for (int tt = 0; tt < 4; ++tt) {
                const int t = tp * 4 + tt;
                __syncthreads();   // previous round's s_spike reads done
                {
                    u16x8 v = (u16x8)0;
                    if (!(dr == 12 && scg >= 2)) {   // cols >= 784 stay zero (KP-pad)
                        unsigned word = s_packed[t * (WG_ROWS * WPR) + sr * WPR + dr * 4 + (scg >> 1)];
                        unsigned bits = (word >> ((scg & 1) * 16)) & 0xFFFFu;
#pragma unroll
                        for (int j = 0; j < 8; ++j) {
                            unsigned two = (bits >> (2 * j)) & 3u;
                            v[j] = (two & 1u) ? ((two & 2u) ? (unsigned short)0xBF80
                                                            : (unsigned short)0x3F80)
                                              : (unsigned short)0;
                        }
                    }
                    *reinterpret_cast<u16x8*>(reinterpret_cast<char*>(s_spike) + swByte) = v;
                }
                __syncthreads();   // spikes visible
#pragma unroll
                for (int c = 0; c < 2; ++c) {
                    const int rr = m_off + l15;
                    const int g = (c * 4 + l4) ^ (rr & 7);
                    bf16x8 a = *reinterpret_cast<const bf16x8*>(
                        reinterpret_cast<const char*>(s_spike) + rr * 128 + g * 16);
#pragma unroll
                    for (int nt = 0; nt < 4; ++nt) {
                        acc[tt][nt] = __builtin_amdgcn_mfma_f32_16x16x32_bf16(a, bh[c][nt],  acc[tt][nt], 0, 0, 0);
                        acc[tt][nt] = __builtin_amdgcn_mfma_f32_16x16x32_bf16(a, blo[c][nt], acc[tt][nt], 0, 0, 0);
                    }
                }
            }
        }
#pragma unroll
        for (int tt = 0; tt < 4; ++tt)
#pragma unroll
            for (int nt = 0; nt < 4; ++nt)
#pragma unroll
                for (int r = 0; r < 4; ++r) {
                    float m = 0.95f * mem1[nt][r] + acc[tt][nt][r];
                    m = m + b1f[nt];
                    float o = (m > 1.0f) ? 1.0f : 0.0f;
                    mem1[nt][r] = m - o;
                    cnt[nt][r] += o;
                }
    }

    __syncthreads();
#pragma unroll
    for (int nt = 0; nt < 4; ++nt)
#pragma unroll
        for (int r = 0; r < 4; ++r)
            s_cnt[m_off + l4 * 4 + r][n_off + nt * 16 + l15] = cnt[nt][r];
    __syncthreads();
    for (int idx = tid; idx < WG_ROWS * C_DIM; idx += 256) {
        int bl_ = idx / C_DIM, c = idx - bl_ * C_DIM;
        float s = 0.0f;
        for (int h = 0; h < H_DIM; ++h) s += s_cnt[bl_][h] * W2[c * H_DIM + h];
        out[(size_t)(row0 + bl_) * C_DIM + c] = s * 0.125f + b2[c];
    }
}

// ---------------- fallback: verbatim round-1 fused kernel (used if ws too small) ----------------
__global__ __launch_bounds__(256, 2)
void snn_main(const float* __restrict__ inp, const float* __restrict__ rnd,
              const unsigned short* __restrict__ w1hi, const unsigned short* __restrict__ w1lo,
              const float* __restrict__ b1p, const float* __restrict__ W2,
              const float* __restrict__ b2, float* __restrict__ out)
{
    __shared__ __align__(16) unsigned short s_spike[WG_ROWS * 64];
    __shared__ float s_cnt[WG_ROWS][HP];

    const int tid  = threadIdx.x;
    const int lane = tid & 63;
    const int wid  = tid >> 6;
    const int m_off = (wid >> 1) * 16;
    const int n_off = (wid & 1) * 64;
    const int row0 = blockIdx.x * WG_ROWS;
    const int l15 = lane & 15;
    const int l4  = lane >> 4;

    float b1f[4];
#pragma unroll
    for (int nt = 0; nt < 4; ++nt) b1f[nt] = b1p[n_off + nt * 16 + l15];

    f32x4 mem1[4], cnt[4];
#pragma unroll
    for (int nt = 0; nt < 4; ++nt) { mem1[nt] = (f32x4)0.0f; cnt[nt] = (f32x4)0.0f; }

    const int sr  = tid >> 3;
    const int scg = tid & 7;
    const size_t inp_base = (size_t)(row0 + sr) * D_IN;
    const int swByte = (sr * 8 + (scg ^ (sr & 7))) * 16;

    for (int tp = 0; tp < 2; ++tp) {
        f32x4 acc[4][4];
#pragma unroll
        for (int a_ = 0; a_ < 4; ++a_)
#pragma unroll
            for (int b_ = 0; b_ < 4; ++b_) acc[a_][b_] = (f32x4)0.0f;

        for (int dr = 0; dr < NDR; ++dr) {
            const int kbase = dr * 64;
            bf16x8 bh[2][4], blo[2][4];
#pragma unroll
            for (int c = 0; c < 2; ++c)
#pragma unroll
                for (int nt = 0; nt < 4; ++nt) {
                    int off = (n_off + nt * 16 + l15) * KP + kbase + c * 32 + l4 * 8;
                    bh[c][nt]  = *reinterpret_cast<const bf16x8*>(w1hi + off);
                    blo[c][nt] = *reinterpret_cast<const bf16x8*>(w1lo + off);
                }
#pragma unroll
            for (int tt = 0; tt < 4; ++tt) {
                const int t = tp * 4 + tt;
                __syncthreads();
                {
                    const int gd = kbase + scg * 8;
                    u16x8 v = (u16x8)0;
                    if (gd + 8 <= D_IN) {
                        const f32x4* rp = reinterpret_cast<const f32x4*>(
                            rnd + (size_t)t * ((size_t)B_TOT * D_IN) + inp_base + gd);
                        const f32x4* ip = reinterpret_cast<const f32x4*>(inp + inp_base + gd);
                        f32x4 r0 = rp[0], r1 = rp[1];
                        f32x4 i0 = ip[0], i1 = ip[1];
                        float xs[8] = {i0[0],i0[1],i0[2],i0[3],i1[0],i1[1],i1[2],i1[3]};
                        float rs[8] = {r0[0],r0[1],r0[2],r0[3],r1[0],r1[1],r1[2],r1[3]};
#pragma unroll
                        for (int j = 0; j < 8; ++j) {
                            unsigned short sg = xs[j] > 0.0f ? (unsigned short)0x3F80
                                              : (xs[j] < 0.0f ? (unsigned short)0xBF80
                                                              : (unsigned short)0);
                            v[j] = (rs[j] * 2.0f <= fabsf(xs[j])) ? sg : (unsigned short)0;
                        }
                    }
                    *reinterpret_cast<u16x8*>(reinterpret_cast<char*>(s_spike) + swByte) = v;
                }
                __syncthreads();
#pragma unroll
                for (int c = 0; c < 2; ++c) {
                    const int rr = m_off + l15;
                    const int g = (c * 4 + l4) ^ (rr & 7);
                    bf16x8 a = *reinterpret_cast<const bf16x8*>(
                        reinterpret_cast<const char*>(s_spike) + rr * 128 + g * 16);
#pragma unroll
                    for (int nt = 0; nt < 4; ++nt) {
                        acc[tt][nt] = __builtin_amdgcn_mfma_f32_16x16x32_bf16(a, bh[c][nt],  acc[tt][nt], 0, 0, 0);
                        acc[tt][nt] = __builtin_amdgcn_mfma_f32_16x16x32_bf16(a, blo[c][nt], acc[tt][nt], 0, 0, 0);
                    }
                }
            }
        }
#pragma unroll
        for (int tt = 0; tt < 4; ++tt)
#pragma unroll
            for (int nt = 0; nt < 4; ++nt)
#pragma unroll
                for (int r = 0; r < 4; ++r) {
                    float m = 0.95f * mem1[nt][r] + acc[tt][nt][r];
                    m = m + b1f[nt];
                    float o = (m > 1.0f) ? 1.0f : 0.0f;
                    mem1[nt][r] = m - o;
                    cnt[nt][r] += o;
                }
    }

    __syncthreads();
#pragma unroll
    for (int nt = 0; nt < 4; ++nt)
#pragma unroll
        for (int r = 0; r < 4; ++r)
            s_cnt[m_off + l4 * 4 + r][n_off + nt * 16 + l15] = cnt[nt][r];
    __syncthreads();
    for (int idx = tid; idx < WG_ROWS * C_DIM; idx += 256) {
        int bl_ = idx / C_DIM, c = idx - bl_ * C_DIM;
        float s = 0.0f;
        for (int h = 0; h < H_DIM; ++h) s += s_cnt[bl_][h] * W2[c * H_DIM + h];
        out[(size_t)(row0 + bl_) * C_DIM + c] = s * 0.125f + b2[c];
    }
}

extern "C" void kernel_launch(void* const* d_in, const int* in_sizes, int n_in,
                              void* d_out, int out_size, void* d_ws, size_t ws_size,
                              hipStream_t stream) {
    const float* inp = (const float*)d_in[0];
    const float* rnd = (const float*)d_in[1];
    const float* W1  = (const float*)d_in[2];
    const float* b1  = (const float*)d_in[3];
    const float* W2  = (const float*)d_in[4];
    const float* b2  = (const float*)d_in[5];
    float* out = (float*)d_out;

    unsigned short* w1hi = (unsigned short*)d_ws;
    unsigned short* w1lo = w1hi + HP * KP;
    float* b1p = (float*)(w1lo + HP * KP);
    unsigned* packed = (unsigned*)(b1p + HP);   // offset 426,496 B

    const size_t needed = 426496 + (size_t)NWORDS * 4;

    prep_kernel<<<(HP * KP + 255) / 256, 256, 0, stream>>>(W1, b1, w1hi, w1lo, b1p);

    if (ws_size >= needed) {
        spike_pack<<<2048, 256, 0, stream>>>(inp, rnd, packed);
        snn_gemm<<<B_TOT / WG_ROWS, 256, 0, stream>>>(packed, w1hi, w1lo, b1p, W2, b2, out);
    } else {
        snn_main<<<B_TOT / WG_ROWS, 256, 0, stream>>>(inp, rnd, w1hi, w1lo, b1p, W2, b2, out);
    }
}